// Round 4
// baseline (392.666 us; speedup 1.0000x reference)
//
#include <hip/hip_runtime.h>

typedef unsigned short u16;
typedef __bf16 bf16x8 __attribute__((ext_vector_type(8)));
typedef float f32x4 __attribute__((ext_vector_type(4)));

#define B_    128
#define S_    416
#define NPEP  32
#define MMHC  384
#define D_    256
#define H_    8
#define E_    32
#define O_    256
#define BS_   (B_ * S_)      /* 53248 */

#define PAD_TOK (-2.0f)
// Underflows exp() to exact 0, safe under any expf range reduction.
#define MASK_SENT (-3.0e4f)

__device__ __forceinline__ float bf2f(u16 u) {
  union { unsigned int i; float f; } x; x.i = ((unsigned int)u) << 16; return x.f;
}
__device__ __forceinline__ u16 f2bf(float f) {
  union { float f; unsigned int i; } x; x.f = f;
  unsigned int i = x.i;
  return (u16)((i + 0x7FFFu + ((i >> 16) & 1u)) >> 16);  // RNE
}

// ---------------------------------------------------------------------------
// K0: pack weights fp32 -> bf16.
//  blocks 0..1023 : WT[col][d] = {q,k,v,g}_proj[h][d][e], col = p*256 + h*32 + e
//  blocks 1024..1279 : WoT[n][k] = out_w[k][n]
// ---------------------------------------------------------------------------
__global__ __launch_bounds__(256)
void pack_w(const float* __restrict__ q, const float* __restrict__ k,
            const float* __restrict__ v, const float* __restrict__ g,
            const float* __restrict__ ow, u16* __restrict__ WT, u16* __restrict__ WoT) {
  const int bx = blockIdx.x, t = threadIdx.x;
  if (bx < 1024) {
    const int col = bx;
    const int p = col >> 8, h = (col >> 5) & 7, e = col & 31;
    const float* src = (p == 0) ? q : (p == 1) ? k : (p == 2) ? v : g;
    WT[col * 256 + t] = f2bf(src[(h * 256 + t) * 32 + e]);
  } else {
    const int n = bx - 1024;
    WoT[n * 256 + t] = f2bf(ow[t * 256 + n]);
  }
}

// ---------------------------------------------------------------------------
// LN1: fp32 in -> bf16 out. One wave per row (256 cols), 4 rows/block.
// ---------------------------------------------------------------------------
__global__ __launch_bounds__(256)
void ln_f2b(const float* __restrict__ inp, u16* __restrict__ out,
            const float* __restrict__ gam, const float* __restrict__ bet) {
  const int w = threadIdx.x >> 6, lane = threadIdx.x & 63;
  const size_t row = (size_t)blockIdx.x * 4 + w;
  const float4 u = *((const float4*)inp + row * 64 + lane);
  const float x0 = u.x, x1 = u.y, x2 = u.z, x3 = u.w;
  float sum = (x0 + x1) + (x2 + x3);
  float ss  = (x0 * x0 + x1 * x1) + (x2 * x2 + x3 * x3);
  #pragma unroll
  for (int off = 32; off; off >>= 1) {
    sum += __shfl_xor(sum, off);
    ss  += __shfl_xor(ss, off);
  }
  const float mean = sum * 0.00390625f;
  float var = ss * 0.00390625f - mean * mean;
  var = fmaxf(var, 0.0f);
  const float rs = rsqrtf(var + 1e-6f);
  const float4 g4 = *((const float4*)gam + lane);
  const float4 b4 = *((const float4*)bet + lane);
  ushort4 r;
  r.x = f2bf((x0 - mean) * rs * g4.x + b4.x);
  r.y = f2bf((x1 - mean) * rs * g4.y + b4.y);
  r.z = f2bf((x2 - mean) * rs * g4.z + b4.z);
  r.w = f2bf((x3 - mean) * rs * g4.w + b4.w);
  *((ushort4*)out + row * 64 + lane) = r;
}

// ---------------------------------------------------------------------------
// LN2: fp32 in -> fp32 out, safe in-place (each thread RMWs its own float4).
// ---------------------------------------------------------------------------
__global__ __launch_bounds__(256)
void ln_f2f(const float* __restrict__ inp, float* __restrict__ out,
            const float* __restrict__ gam, const float* __restrict__ bet) {
  const int w = threadIdx.x >> 6, lane = threadIdx.x & 63;
  const size_t row = (size_t)blockIdx.x * 4 + w;
  const float4 u = *((const float4*)inp + row * 64 + lane);
  const float x0 = u.x, x1 = u.y, x2 = u.z, x3 = u.w;
  float sum = (x0 + x1) + (x2 + x3);
  float ss  = (x0 * x0 + x1 * x1) + (x2 * x2 + x3 * x3);
  #pragma unroll
  for (int off = 32; off; off >>= 1) {
    sum += __shfl_xor(sum, off);
    ss  += __shfl_xor(ss, off);
  }
  const float mean = sum * 0.00390625f;
  float var = ss * 0.00390625f - mean * mean;
  var = fmaxf(var, 0.0f);
  const float rs = rsqrtf(var + 1e-6f);
  const float4 g4 = *((const float4*)gam + lane);
  const float4 b4 = *((const float4*)bet + lane);
  float4 r;
  r.x = (x0 - mean) * rs * g4.x + b4.x;
  r.y = (x1 - mean) * rs * g4.y + b4.y;
  r.z = (x2 - mean) * rs * g4.z + b4.z;
  r.w = (x3 - mean) * rs * g4.w + b4.w;
  *((float4*)out + row * 64 + lane) = r;
}

// ---------------------------------------------------------------------------
// MFMA GEMM: C[M x Ntot] = A[M x 256] * BT[Ntot x 256]^T, bf16 inputs.
// 128x128 tile, 4 waves 2x2, 64x64/wave via 4x4 of 16x16x32 MFMAs.
// F32OUT: add fp32 bias[col], store fp32; else store bf16.
// ---------------------------------------------------------------------------
template<bool F32OUT>
__global__ __launch_bounds__(256, 2)
void gemm_bt(const u16* __restrict__ A, const u16* __restrict__ BT,
             void* __restrict__ Cv, const float* __restrict__ bias, const int ldc) {
  __shared__ u16 As[128][72];   // 144B row stride (9*16) keeps b128 aligned
  __shared__ u16 Bs[128][72];
  const int n0 = blockIdx.x * 128;
  const int m0 = blockIdx.y * 128;
  const int tid = threadIdx.x;
  const int lane = tid & 63;
  const int w = tid >> 6;
  const int wr = (w >> 1) * 64;
  const int wc = (w & 1) * 64;
  const int mi = lane & 15;
  const int quad = lane >> 4;
  f32x4 acc[4][4] = {};
  for (int kc = 0; kc < 256; kc += 64) {
    __syncthreads();
    #pragma unroll
    for (int j = 0; j < 4; ++j) {
      const int idx = tid + j * 256;       // 0..1023
      const int r = idx >> 3;              // 0..127
      const int c = (idx & 7) * 8;         // 0..56
      *(uint4*)&As[r][c] = *(const uint4*)&A[(size_t)(m0 + r) * 256 + kc + c];
      *(uint4*)&Bs[r][c] = *(const uint4*)&BT[(size_t)(n0 + r) * 256 + kc + c];
    }
    __syncthreads();
    #pragma unroll
    for (int kt = 0; kt < 2; ++kt) {
      const int ko = kt * 32 + quad * 8;
      bf16x8 a[4], bf[4];
      #pragma unroll
      for (int i = 0; i < 4; ++i) a[i]  = *(const bf16x8*)&As[wr + i * 16 + mi][ko];
      #pragma unroll
      for (int i = 0; i < 4; ++i) bf[i] = *(const bf16x8*)&Bs[wc + i * 16 + mi][ko];
      #pragma unroll
      for (int i = 0; i < 4; ++i)
        #pragma unroll
        for (int jn = 0; jn < 4; ++jn)
          acc[i][jn] = __builtin_amdgcn_mfma_f32_16x16x32_bf16(a[i], bf[jn], acc[i][jn], 0, 0, 0);
    }
  }
  // D: row = quad*4 + reg, col = lane&15
  #pragma unroll
  for (int i = 0; i < 4; ++i) {
    const int row = m0 + wr + i * 16 + quad * 4;
    #pragma unroll
    for (int jn = 0; jn < 4; ++jn) {
      const int col = n0 + wc + jn * 16 + mi;
      const float bv = F32OUT ? bias[col] : 0.0f;
      #pragma unroll
      for (int r = 0; r < 4; ++r) {
        const float vv = acc[i][jn][r] + bv;
        if (F32OUT) ((float*)Cv)[(size_t)(row + r) * ldc + col] = vv;
        else        ((u16*)Cv)[(size_t)(row + r) * ldc + col] = f2bf(vv);
      }
    }
  }
}

// ---------------------------------------------------------------------------
// Attention, MHC rows: attend to the 32 peptide keys. One block per (local b, h),
// 384 threads = one per row. QKVG is CHUNK-LOCAL (b0 = first global batch).
// QKVG layout: [b_loc*S+s][p*256 + h*32 + e], p: 0=Q 1=K 2=V 3=G. Masks fp32.
// ---------------------------------------------------------------------------
__global__ __launch_bounds__(384)
void att_mhc(const u16* __restrict__ QKVG, const float* __restrict__ p_mask,
             const float* __restrict__ m_mask, u16* __restrict__ att, const int b0) {
  __shared__ float Kp[32][32];
  __shared__ float Vp[32][32];
  __shared__ float pf[32];
  const int bh = blockIdx.x;
  const int bl = bh >> 3, h = bh & 7;
  const int b = b0 + bl;
  const int t = threadIdx.x;
  const size_t base = (size_t)(bl * S_) * 1024 + h * 32;
  if (t < 256) {
    const int y = t >> 3, e0 = (t & 7) * 4;
    const ushort4 ku = *(const ushort4*)&QKVG[base + (size_t)y * 1024 + 256 + e0];
    Kp[y][e0 + 0] = bf2f(ku.x); Kp[y][e0 + 1] = bf2f(ku.y);
    Kp[y][e0 + 2] = bf2f(ku.z); Kp[y][e0 + 3] = bf2f(ku.w);
    const ushort4 vu = *(const ushort4*)&QKVG[base + (size_t)y * 1024 + 512 + e0];
    Vp[y][e0 + 0] = bf2f(vu.x); Vp[y][e0 + 1] = bf2f(vu.y);
    Vp[y][e0 + 2] = bf2f(vu.z); Vp[y][e0 + 3] = bf2f(vu.w);
  } else if (t < 288) {
    const int y = t - 256;
    pf[y] = (p_mask[b * NPEP + y] == PAD_TOK) ? 0.0f : 1.0f;
  }
  __syncthreads();
  const int x = 32 + t;
  const size_t lrow = (size_t)(bl * S_ + x);
  float q[32];
  {
    const u16* qp = &QKVG[lrow * 1024 + h * 32];
    #pragma unroll
    for (int j = 0; j < 8; ++j) {
      const ushort4 u = *(const ushort4*)&qp[4 * j];
      q[4 * j + 0] = bf2f(u.x); q[4 * j + 1] = bf2f(u.y);
      q[4 * j + 2] = bf2f(u.z); q[4 * j + 3] = bf2f(u.w);
    }
  }
  float s[32];
  #pragma unroll
  for (int y = 0; y < 32; ++y) {
    float a0 = 0, a1 = 0, a2 = 0, a3 = 0;
    #pragma unroll
    for (int j = 0; j < 8; ++j) {
      const float4 k4 = *(const float4*)&Kp[y][4 * j];
      a0 += q[4 * j + 0] * k4.x; a1 += q[4 * j + 1] * k4.y;
      a2 += q[4 * j + 2] * k4.z; a3 += q[4 * j + 3] * k4.w;
    }
    const float sv = ((a0 + a1) + (a2 + a3)) * 0.17677669529663687f; // 1/sqrt(32)
    s[y] = (pf[y] > 0.0f) ? sv : MASK_SENT;
  }
  float mx = MASK_SENT;
  #pragma unroll
  for (int y = 0; y < 32; ++y) mx = fmaxf(mx, s[y]);
  float tot = 0.0f;
  #pragma unroll
  for (int y = 0; y < 32; ++y) { s[y] = __expf(s[y] - mx); tot += s[y]; }
  const float inv = (tot > 0.0f) ? (1.0f / tot) : 0.0f;
  float o[32];
  #pragma unroll
  for (int e = 0; e < 32; ++e) o[e] = 0.0f;
  #pragma unroll
  for (int y = 0; y < 32; ++y) {
    const float p = s[y] * inv;
    #pragma unroll
    for (int j = 0; j < 8; ++j) {
      const float4 v4 = *(const float4*)&Vp[y][4 * j];
      o[4 * j + 0] += p * v4.x; o[4 * j + 1] += p * v4.y;
      o[4 * j + 2] += p * v4.z; o[4 * j + 3] += p * v4.w;
    }
  }
  const float rf = (m_mask[b * MMHC + t] == PAD_TOK) ? 0.0f : 1.0f;
  const u16* gp = &QKVG[lrow * 1024 + 768 + h * 32];
  u16* op = &att[(size_t)(b * S_ + x) * 256 + h * 32];
  #pragma unroll
  for (int j = 0; j < 8; ++j) {
    const ushort4 gu = *(const ushort4*)&gp[4 * j];
    ushort4 r;
    r.x = f2bf(o[4 * j + 0] * rf / (1.0f + __expf(-bf2f(gu.x))));
    r.y = f2bf(o[4 * j + 1] * rf / (1.0f + __expf(-bf2f(gu.y))));
    r.z = f2bf(o[4 * j + 2] * rf / (1.0f + __expf(-bf2f(gu.z))));
    r.w = f2bf(o[4 * j + 3] * rf / (1.0f + __expf(-bf2f(gu.w))));
    *(ushort4*)&op[4 * j] = r;
  }
}

// ---------------------------------------------------------------------------
// Attention, peptide rows: attend to 384 MHC keys. One block per (local b, h).
// ---------------------------------------------------------------------------
__global__ __launch_bounds__(384)
void att_pep(const u16* __restrict__ QKVG, const float* __restrict__ p_mask,
             const float* __restrict__ m_mask, u16* __restrict__ att, const int b0) {
  __shared__ float Qs[32][32];
  __shared__ float Ss[32][392];
  __shared__ u16  VmT[32][392];   // row stride 784B = 49*16
  __shared__ float pf[32];
  const int bh = blockIdx.x;
  const int bl = bh >> 3, h = bh & 7;
  const int b = b0 + bl;
  const int t = threadIdx.x;
  const size_t base = (size_t)(bl * S_) * 1024 + h * 32;
  if (t < 256) {
    const int r = t >> 3, e0 = (t & 7) * 4;
    const ushort4 u = *(const ushort4*)&QKVG[base + (size_t)r * 1024 + e0];
    const float sc = 0.17677669529663687f;
    Qs[r][e0 + 0] = bf2f(u.x) * sc; Qs[r][e0 + 1] = bf2f(u.y) * sc;
    Qs[r][e0 + 2] = bf2f(u.z) * sc; Qs[r][e0 + 3] = bf2f(u.w) * sc;
  } else if (t < 288) {
    const int r = t - 256;
    pf[r] = (p_mask[b * NPEP + r] == PAD_TOK) ? 0.0f : 1.0f;
  }
  const int y = t;
  float k[32];
  {
    const u16* kp = &QKVG[base + (size_t)(32 + y) * 1024 + 256];
    #pragma unroll
    for (int j = 0; j < 8; ++j) {
      const ushort4 u = *(const ushort4*)&kp[4 * j];
      k[4 * j + 0] = bf2f(u.x); k[4 * j + 1] = bf2f(u.y);
      k[4 * j + 2] = bf2f(u.z); k[4 * j + 3] = bf2f(u.w);
    }
    const u16* vp = &QKVG[base + (size_t)(32 + y) * 1024 + 512];
    #pragma unroll
    for (int j = 0; j < 8; ++j) {
      const ushort4 u = *(const ushort4*)&vp[4 * j];
      VmT[4 * j + 0][y] = u.x; VmT[4 * j + 1][y] = u.y;
      VmT[4 * j + 2][y] = u.z; VmT[4 * j + 3][y] = u.w;
    }
  }
  const float mf = (m_mask[b * MMHC + y] == PAD_TOK) ? 0.0f : 1.0f;
  __syncthreads();
  #pragma unroll 4
  for (int r = 0; r < 32; ++r) {
    float a0 = 0, a1 = 0, a2 = 0, a3 = 0;
    #pragma unroll
    for (int j = 0; j < 8; ++j) {
      const float4 q4 = *(const float4*)&Qs[r][4 * j];
      a0 += q4.x * k[4 * j + 0]; a1 += q4.y * k[4 * j + 1];
      a2 += q4.z * k[4 * j + 2]; a3 += q4.w * k[4 * j + 3];
    }
    Ss[r][y] = (mf > 0.0f) ? ((a0 + a1) + (a2 + a3)) : MASK_SENT;
  }
  __syncthreads();
  const int wv = t >> 6, lane = t & 63;
  for (int r = wv; r < 32; r += 6) {
    float v[6];
    #pragma unroll
    for (int j = 0; j < 6; ++j) v[j] = Ss[r][lane + 64 * j];
    float mx = v[0];
    #pragma unroll
    for (int j = 1; j < 6; ++j) mx = fmaxf(mx, v[j]);
    #pragma unroll
    for (int off = 32; off; off >>= 1) mx = fmaxf(mx, __shfl_xor(mx, off));
    float e[6]; float tot = 0.0f;
    #pragma unroll
    for (int j = 0; j < 6; ++j) { e[j] = __expf(v[j] - mx); tot += e[j]; }
    #pragma unroll
    for (int off = 32; off; off >>= 1) tot += __shfl_xor(tot, off);
    const float inv = (tot > 0.0f) ? (1.0f / tot) : 0.0f;
    #pragma unroll
    for (int j = 0; j < 6; ++j) Ss[r][lane + 64 * j] = e[j] * inv;
  }
  __syncthreads();
  const int e = t & 31, rg = t >> 5;
  const int r0 = rg, r1 = rg + 12, r2 = rg + 24;
  const bool has2 = (rg < 8);
  float o0 = 0.0f, o1 = 0.0f, o2 = 0.0f;
  for (int yg = 0; yg < 48; ++yg) {
    float vv[8];
    {
      const u16* vp8 = &VmT[e][yg * 8];
      const ushort4 ua = *(const ushort4*)vp8;
      const ushort4 ub = *(const ushort4*)(vp8 + 4);
      vv[0] = bf2f(ua.x); vv[1] = bf2f(ua.y); vv[2] = bf2f(ua.z); vv[3] = bf2f(ua.w);
      vv[4] = bf2f(ub.x); vv[5] = bf2f(ub.y); vv[6] = bf2f(ub.z); vv[7] = bf2f(ub.w);
    }
    const float4 pa0 = *(const float4*)&Ss[r0][yg * 8];
    const float4 pb0 = *(const float4*)&Ss[r0][yg * 8 + 4];
    o0 += pa0.x * vv[0] + pa0.y * vv[1] + pa0.z * vv[2] + pa0.w * vv[3]
        + pb0.x * vv[4] + pb0.y * vv[5] + pb0.z * vv[6] + pb0.w * vv[7];
    const float4 pa1 = *(const float4*)&Ss[r1][yg * 8];
    const float4 pb1 = *(const float4*)&Ss[r1][yg * 8 + 4];
    o1 += pa1.x * vv[0] + pa1.y * vv[1] + pa1.z * vv[2] + pa1.w * vv[3]
        + pb1.x * vv[4] + pb1.y * vv[5] + pb1.z * vv[6] + pb1.w * vv[7];
    if (has2) {
      const float4 pa2 = *(const float4*)&Ss[r2][yg * 8];
      const float4 pb2 = *(const float4*)&Ss[r2][yg * 8 + 4];
      o2 += pa2.x * vv[0] + pa2.y * vv[1] + pa2.z * vv[2] + pa2.w * vv[3]
          + pb2.x * vv[4] + pb2.y * vv[5] + pb2.z * vv[6] + pb2.w * vv[7];
    }
  }
  {
    const size_t orow = (size_t)(b * S_) * 256 + h * 32 + e;
    const float g0 = bf2f(QKVG[base + (size_t)r0 * 1024 + 768 + e]);
    att[orow + (size_t)r0 * 256] = f2bf(o0 * pf[r0] / (1.0f + __expf(-g0)));
    const float g1 = bf2f(QKVG[base + (size_t)r1 * 1024 + 768 + e]);
    att[orow + (size_t)r1 * 256] = f2bf(o1 * pf[r1] / (1.0f + __expf(-g1)));
    if (has2) {
      const float g2 = bf2f(QKVG[base + (size_t)r2 * 1024 + 768 + e]);
      att[orow + (size_t)r2 * 256] = f2bf(o2 * pf[r2] / (1.0f + __expf(-g2)));
    }
  }
}

// ---------------------------------------------------------------------------
// Launch. All d_in are fp32 (reference dtypes); d_out is fp32.
// Workspace (ws_size-adaptive; QKVG chunked over batches):
//   WT   @ 0        : 524288   (bf16)
//   WoT  @ 524288   : 131072   (bf16)
//   attx @ 655360   : BS*256*2 = 27262976  (bf16; LN1 out, then attention out)
//   QKVG @ 27918336 : nb*416*1024*2 per chunk (nb in {32,16,8,4} by ws_size)
// gemm2 writes fp32+bias into d_out; LN2 in-place on d_out.
// ---------------------------------------------------------------------------
extern "C" void kernel_launch(void* const* d_in, const int* in_sizes, int n_in,
                              void* d_out, int out_size, void* d_ws, size_t ws_size,
                              hipStream_t stream) {
  const float* x      = (const float*)d_in[0];
  const float* p_mask = (const float*)d_in[1];
  const float* m_mask = (const float*)d_in[2];
  const float* q_proj = (const float*)d_in[3];
  const float* k_proj = (const float*)d_in[4];
  const float* v_proj = (const float*)d_in[5];
  const float* g_proj = (const float*)d_in[6];
  const float* out_w  = (const float*)d_in[7];
  const float* out_b  = (const float*)d_in[8];
  const float* ln1_g  = (const float*)d_in[9];
  const float* ln1_b  = (const float*)d_in[10];
  const float* ln2_g  = (const float*)d_in[11];
  const float* ln2_b  = (const float*)d_in[12];

  char* ws = (char*)d_ws;
  u16* WT   = (u16*)(ws);
  u16* WoT  = (u16*)(ws + 524288);
  u16* attx = (u16*)(ws + 655360);
  u16* QKVG = (u16*)(ws + 27918336);
  float* outp = (float*)d_out;

  // pick chunk size (batches) from actual workspace size; nb must be mult of 4
  const size_t FIXED = 27918336;
  const size_t PER_B = (size_t)S_ * 1024 * 2;   // 851968
  int nb = 4;
  const int cands[4] = {32, 16, 8, 4};
  for (int i = 0; i < 4; ++i) {
    if (FIXED + (size_t)cands[i] * PER_B <= ws_size) { nb = cands[i]; break; }
  }
  const int nchunks = B_ / nb;

  hipLaunchKernelGGL(pack_w, dim3(1280), dim3(256), 0, stream,
                     q_proj, k_proj, v_proj, g_proj, out_w, WT, WoT);
  hipLaunchKernelGGL(ln_f2b, dim3(BS_ / 4), dim3(256), 0, stream,
                     x, attx, ln1_g, ln1_b);
  for (int c = 0; c < nchunks; ++c) {
    const int b0 = c * nb;
    const u16* Achunk = attx + (size_t)b0 * S_ * 256;
    hipLaunchKernelGGL((gemm_bt<false>), dim3(8, nb * S_ / 128), dim3(256), 0, stream,
                       Achunk, WT, (void*)QKVG, (const float*)nullptr, 1024);
    hipLaunchKernelGGL(att_mhc, dim3(nb * 8), dim3(384), 0, stream,
                       QKVG, p_mask, m_mask, attx, b0);
    hipLaunchKernelGGL(att_pep, dim3(nb * 8), dim3(384), 0, stream,
                       QKVG, p_mask, m_mask, attx, b0);
  }
  hipLaunchKernelGGL((gemm_bt<true>), dim3(2, BS_ / 128), dim3(256), 0, stream,
                     attx, WoT, (void*)outp, out_b, 256);
  hipLaunchKernelGGL(ln_f2f, dim3(BS_ / 4), dim3(256), 0, stream,
                     outp, outp, ln2_g, ln2_b);
}

// Round 5
// 348.938 us; speedup vs baseline: 1.1253x; 1.1253x over previous
//
#include <hip/hip_runtime.h>

typedef unsigned short u16;
typedef __bf16 bf16x8 __attribute__((ext_vector_type(8)));
typedef float f32x4 __attribute__((ext_vector_type(4)));

#define B_    128
#define S_    416
#define NPEP  32
#define MMHC  384
#define D_    256
#define H_    8
#define E_    32
#define O_    256
#define BS_   (B_ * S_)      /* 53248 */

#define PAD_TOK (-2.0f)
// Underflows exp() to exact 0, safe under any expf range reduction.
#define MASK_SENT (-3.0e4f)

typedef const __attribute__((address_space(1))) void cg_void;
typedef __attribute__((address_space(3))) void lds_void;

__device__ __forceinline__ float bf2f(u16 u) {
  union { unsigned int i; float f; } x; x.i = ((unsigned int)u) << 16; return x.f;
}
__device__ __forceinline__ u16 f2bf(float f) {
  union { float f; unsigned int i; } x; x.f = f;
  unsigned int i = x.i;
  return (u16)((i + 0x7FFFu + ((i >> 16) & 1u)) >> 16);  // RNE
}

// ---------------------------------------------------------------------------
// K0: pack weights fp32 -> bf16.
//  blocks 0..1023 : WT[col][d] = {q,k,v,g}_proj[h][d][e], col = p*256 + h*32 + e
//  blocks 1024..1279 : WoT[n][k] = out_w[k][n]
// ---------------------------------------------------------------------------
__global__ __launch_bounds__(256)
void pack_w(const float* __restrict__ q, const float* __restrict__ k,
            const float* __restrict__ v, const float* __restrict__ g,
            const float* __restrict__ ow, u16* __restrict__ WT, u16* __restrict__ WoT) {
  const int bx = blockIdx.x, t = threadIdx.x;
  if (bx < 1024) {
    const int col = bx;
    const int p = col >> 8, h = (col >> 5) & 7, e = col & 31;
    const float* src = (p == 0) ? q : (p == 1) ? k : (p == 2) ? v : g;
    WT[col * 256 + t] = f2bf(src[(h * 256 + t) * 32 + e]);
  } else {
    const int n = bx - 1024;
    WoT[n * 256 + t] = f2bf(ow[t * 256 + n]);
  }
}

// ---------------------------------------------------------------------------
// LN1: fp32 in -> bf16 out. One wave per row (256 cols), 4 rows/block.
// ---------------------------------------------------------------------------
__global__ __launch_bounds__(256)
void ln_f2b(const float* __restrict__ inp, u16* __restrict__ out,
            const float* __restrict__ gam, const float* __restrict__ bet) {
  const int w = threadIdx.x >> 6, lane = threadIdx.x & 63;
  const size_t row = (size_t)blockIdx.x * 4 + w;
  const float4 u = *((const float4*)inp + row * 64 + lane);
  const float x0 = u.x, x1 = u.y, x2 = u.z, x3 = u.w;
  float sum = (x0 + x1) + (x2 + x3);
  float ss  = (x0 * x0 + x1 * x1) + (x2 * x2 + x3 * x3);
  #pragma unroll
  for (int off = 32; off; off >>= 1) {
    sum += __shfl_xor(sum, off);
    ss  += __shfl_xor(ss, off);
  }
  const float mean = sum * 0.00390625f;
  float var = ss * 0.00390625f - mean * mean;
  var = fmaxf(var, 0.0f);
  const float rs = rsqrtf(var + 1e-6f);
  const float4 g4 = *((const float4*)gam + lane);
  const float4 b4 = *((const float4*)bet + lane);
  ushort4 r;
  r.x = f2bf((x0 - mean) * rs * g4.x + b4.x);
  r.y = f2bf((x1 - mean) * rs * g4.y + b4.y);
  r.z = f2bf((x2 - mean) * rs * g4.z + b4.z);
  r.w = f2bf((x3 - mean) * rs * g4.w + b4.w);
  *((ushort4*)out + row * 64 + lane) = r;
}

// ---------------------------------------------------------------------------
// LN2: fp32 in -> fp32 out, safe in-place (each thread RMWs its own float4).
// ---------------------------------------------------------------------------
__global__ __launch_bounds__(256)
void ln_f2f(const float* __restrict__ inp, float* __restrict__ out,
            const float* __restrict__ gam, const float* __restrict__ bet) {
  const int w = threadIdx.x >> 6, lane = threadIdx.x & 63;
  const size_t row = (size_t)blockIdx.x * 4 + w;
  const float4 u = *((const float4*)inp + row * 64 + lane);
  const float x0 = u.x, x1 = u.y, x2 = u.z, x3 = u.w;
  float sum = (x0 + x1) + (x2 + x3);
  float ss  = (x0 * x0 + x1 * x1) + (x2 * x2 + x3 * x3);
  #pragma unroll
  for (int off = 32; off; off >>= 1) {
    sum += __shfl_xor(sum, off);
    ss  += __shfl_xor(ss, off);
  }
  const float mean = sum * 0.00390625f;
  float var = ss * 0.00390625f - mean * mean;
  var = fmaxf(var, 0.0f);
  const float rs = rsqrtf(var + 1e-6f);
  const float4 g4 = *((const float4*)gam + lane);
  const float4 b4 = *((const float4*)bet + lane);
  float4 r;
  r.x = (x0 - mean) * rs * g4.x + b4.x;
  r.y = (x1 - mean) * rs * g4.y + b4.y;
  r.z = (x2 - mean) * rs * g4.z + b4.z;
  r.w = (x3 - mean) * rs * g4.w + b4.w;
  *((float4*)out + row * 64 + lane) = r;
}

// ---------------------------------------------------------------------------
// MFMA GEMM with global_load_lds(16B) staging + XOR-swizzled LDS layout.
// C[M x Ntot] = A[M x 256] * BT[Ntot x 256]^T, bf16 inputs.
// 128x128 tile, 4 waves 2x2, 64x64/wave via 4x4 of 16x16x32 MFMAs.
// LDS: unpadded [128][64] u16 per buffer (global_load_lds forbids padding);
// 16B granule stored at physical column (logical ^ (row & 7)) -> the
// ds_read_b128 fragment reads hit 2 lanes/bank per 16-lane phase (free).
// F32OUT: add fp32 bias[col], store fp32; else store bf16.
// ---------------------------------------------------------------------------
template<bool F32OUT>
__global__ __launch_bounds__(256, 2)
void gemm_bt(const u16* __restrict__ A, const u16* __restrict__ BT,
             void* __restrict__ Cv, const float* __restrict__ bias, const int ldc) {
  __shared__ __attribute__((aligned(16))) u16 As[128 * 64];
  __shared__ __attribute__((aligned(16))) u16 Bs[128 * 64];
  const int n0 = blockIdx.x * 128;
  const int m0 = blockIdx.y * 128;
  const int tid = threadIdx.x;
  const int lane = tid & 63;
  const int w = tid >> 6;
  const int wr = (w >> 1) * 64;
  const int wc = (w & 1) * 64;
  const int mi = lane & 15;
  const int quad = lane >> 4;
  // staging decode: lane -> (row-in-segment, physical granule) ; fetch the
  // swizzled global granule so LDS[r][p] = Global[r][p ^ (r&7)]
  const int rseg = lane >> 3;               // 0..7
  const int gcol = (lane & 7) ^ rseg;       // global 16B-granule to fetch
  f32x4 acc[4][4] = {};
  for (int kc = 0; kc < 256; kc += 64) {
    __syncthreads();
    #pragma unroll
    for (int j = 0; j < 4; ++j) {
      const int seg = w * 4 + j;            // 0..15, 8 rows each
      const int r = seg * 8 + rseg;
      const u16* ga = &A[(size_t)(m0 + r) * 256 + kc + gcol * 8];
      __builtin_amdgcn_global_load_lds((cg_void*)ga, (lds_void*)&As[seg * 512], 16, 0, 0);
      const u16* gb = &BT[(size_t)(n0 + r) * 256 + kc + gcol * 8];
      __builtin_amdgcn_global_load_lds((cg_void*)gb, (lds_void*)&Bs[seg * 512], 16, 0, 0);
    }
    __syncthreads();
    #pragma unroll
    for (int kt = 0; kt < 2; ++kt) {
      bf16x8 a[4], bb[4];
      #pragma unroll
      for (int i = 0; i < 4; ++i) {
        const int m = wr + i * 16 + mi;
        const int pg = (kt * 4 + quad) ^ (mi & 7);
        a[i] = *(const bf16x8*)&As[m * 64 + pg * 8];
      }
      #pragma unroll
      for (int i = 0; i < 4; ++i) {
        const int n = wc + i * 16 + mi;
        const int pg = (kt * 4 + quad) ^ (mi & 7);
        bb[i] = *(const bf16x8*)&Bs[n * 64 + pg * 8];
      }
      #pragma unroll
      for (int i = 0; i < 4; ++i)
        #pragma unroll
        for (int jn = 0; jn < 4; ++jn)
          acc[i][jn] = __builtin_amdgcn_mfma_f32_16x16x32_bf16(a[i], bb[jn], acc[i][jn], 0, 0, 0);
    }
  }
  // D: row = quad*4 + reg, col = lane&15
  #pragma unroll
  for (int i = 0; i < 4; ++i) {
    const int row = m0 + wr + i * 16 + quad * 4;
    #pragma unroll
    for (int jn = 0; jn < 4; ++jn) {
      const int col = n0 + wc + jn * 16 + mi;
      const float bv = F32OUT ? bias[col] : 0.0f;
      #pragma unroll
      for (int r = 0; r < 4; ++r) {
        const float vv = acc[i][jn][r] + bv;
        if (F32OUT) ((float*)Cv)[(size_t)(row + r) * ldc + col] = vv;
        else        ((u16*)Cv)[(size_t)(row + r) * ldc + col] = f2bf(vv);
      }
    }
  }
}

// ---------------------------------------------------------------------------
// Attention, MHC rows: attend to the 32 peptide keys. One block per (local b, h),
// 384 threads = one per row. QKVG is CHUNK-LOCAL (b0 = first global batch).
// QKVG layout: [b_loc*S+s][p*256 + h*32 + e], p: 0=Q 1=K 2=V 3=G. Masks fp32.
// ---------------------------------------------------------------------------
__global__ __launch_bounds__(384)
void att_mhc(const u16* __restrict__ QKVG, const float* __restrict__ p_mask,
             const float* __restrict__ m_mask, u16* __restrict__ att, const int b0) {
  __shared__ float Kp[32][32];
  __shared__ float Vp[32][32];
  __shared__ float pf[32];
  const int bh = blockIdx.x;
  const int bl = bh >> 3, h = bh & 7;
  const int b = b0 + bl;
  const int t = threadIdx.x;
  const size_t base = (size_t)(bl * S_) * 1024 + h * 32;
  if (t < 256) {
    const int y = t >> 3, e0 = (t & 7) * 4;
    const ushort4 ku = *(const ushort4*)&QKVG[base + (size_t)y * 1024 + 256 + e0];
    Kp[y][e0 + 0] = bf2f(ku.x); Kp[y][e0 + 1] = bf2f(ku.y);
    Kp[y][e0 + 2] = bf2f(ku.z); Kp[y][e0 + 3] = bf2f(ku.w);
    const ushort4 vu = *(const ushort4*)&QKVG[base + (size_t)y * 1024 + 512 + e0];
    Vp[y][e0 + 0] = bf2f(vu.x); Vp[y][e0 + 1] = bf2f(vu.y);
    Vp[y][e0 + 2] = bf2f(vu.z); Vp[y][e0 + 3] = bf2f(vu.w);
  } else if (t < 288) {
    const int y = t - 256;
    pf[y] = (p_mask[b * NPEP + y] == PAD_TOK) ? 0.0f : 1.0f;
  }
  __syncthreads();
  const int x = 32 + t;
  const size_t lrow = (size_t)(bl * S_ + x);
  float q[32];
  {
    const u16* qp = &QKVG[lrow * 1024 + h * 32];
    #pragma unroll
    for (int j = 0; j < 8; ++j) {
      const ushort4 u = *(const ushort4*)&qp[4 * j];
      q[4 * j + 0] = bf2f(u.x); q[4 * j + 1] = bf2f(u.y);
      q[4 * j + 2] = bf2f(u.z); q[4 * j + 3] = bf2f(u.w);
    }
  }
  float s[32];
  #pragma unroll
  for (int y = 0; y < 32; ++y) {
    float a0 = 0, a1 = 0, a2 = 0, a3 = 0;
    #pragma unroll
    for (int j = 0; j < 8; ++j) {
      const float4 k4 = *(const float4*)&Kp[y][4 * j];
      a0 += q[4 * j + 0] * k4.x; a1 += q[4 * j + 1] * k4.y;
      a2 += q[4 * j + 2] * k4.z; a3 += q[4 * j + 3] * k4.w;
    }
    const float sv = ((a0 + a1) + (a2 + a3)) * 0.17677669529663687f; // 1/sqrt(32)
    s[y] = (pf[y] > 0.0f) ? sv : MASK_SENT;
  }
  float mx = MASK_SENT;
  #pragma unroll
  for (int y = 0; y < 32; ++y) mx = fmaxf(mx, s[y]);
  float tot = 0.0f;
  #pragma unroll
  for (int y = 0; y < 32; ++y) { s[y] = __expf(s[y] - mx); tot += s[y]; }
  const float inv = (tot > 0.0f) ? (1.0f / tot) : 0.0f;
  float o[32];
  #pragma unroll
  for (int e = 0; e < 32; ++e) o[e] = 0.0f;
  #pragma unroll
  for (int y = 0; y < 32; ++y) {
    const float p = s[y] * inv;
    #pragma unroll
    for (int j = 0; j < 8; ++j) {
      const float4 v4 = *(const float4*)&Vp[y][4 * j];
      o[4 * j + 0] += p * v4.x; o[4 * j + 1] += p * v4.y;
      o[4 * j + 2] += p * v4.z; o[4 * j + 3] += p * v4.w;
    }
  }
  const float rf = (m_mask[b * MMHC + t] == PAD_TOK) ? 0.0f : 1.0f;
  const u16* gp = &QKVG[lrow * 1024 + 768 + h * 32];
  u16* op = &att[(size_t)(b * S_ + x) * 256 + h * 32];
  #pragma unroll
  for (int j = 0; j < 8; ++j) {
    const ushort4 gu = *(const ushort4*)&gp[4 * j];
    ushort4 r;
    r.x = f2bf(o[4 * j + 0] * rf / (1.0f + __expf(-bf2f(gu.x))));
    r.y = f2bf(o[4 * j + 1] * rf / (1.0f + __expf(-bf2f(gu.y))));
    r.z = f2bf(o[4 * j + 2] * rf / (1.0f + __expf(-bf2f(gu.z))));
    r.w = f2bf(o[4 * j + 3] * rf / (1.0f + __expf(-bf2f(gu.w))));
    *(ushort4*)&op[4 * j] = r;
  }
}

// ---------------------------------------------------------------------------
// Attention, peptide rows: attend to 384 MHC keys. One block per (local b, h).
// ---------------------------------------------------------------------------
__global__ __launch_bounds__(384)
void att_pep(const u16* __restrict__ QKVG, const float* __restrict__ p_mask,
             const float* __restrict__ m_mask, u16* __restrict__ att, const int b0) {
  __shared__ float Qs[32][32];
  __shared__ float Ss[32][392];
  __shared__ u16  VmT[32][392];   // row stride 784B = 49*16
  __shared__ float pf[32];
  const int bh = blockIdx.x;
  const int bl = bh >> 3, h = bh & 7;
  const int b = b0 + bl;
  const int t = threadIdx.x;
  const size_t base = (size_t)(bl * S_) * 1024 + h * 32;
  if (t < 256) {
    const int r = t >> 3, e0 = (t & 7) * 4;
    const ushort4 u = *(const ushort4*)&QKVG[base + (size_t)r * 1024 + e0];
    const float sc = 0.17677669529663687f;
    Qs[r][e0 + 0] = bf2f(u.x) * sc; Qs[r][e0 + 1] = bf2f(u.y) * sc;
    Qs[r][e0 + 2] = bf2f(u.z) * sc; Qs[r][e0 + 3] = bf2f(u.w) * sc;
  } else if (t < 288) {
    const int r = t - 256;
    pf[r] = (p_mask[b * NPEP + r] == PAD_TOK) ? 0.0f : 1.0f;
  }
  const int y = t;
  float k[32];
  {
    const u16* kp = &QKVG[base + (size_t)(32 + y) * 1024 + 256];
    #pragma unroll
    for (int j = 0; j < 8; ++j) {
      const ushort4 u = *(const ushort4*)&kp[4 * j];
      k[4 * j + 0] = bf2f(u.x); k[4 * j + 1] = bf2f(u.y);
      k[4 * j + 2] = bf2f(u.z); k[4 * j + 3] = bf2f(u.w);
    }
    const u16* vp = &QKVG[base + (size_t)(32 + y) * 1024 + 512];
    #pragma unroll
    for (int j = 0; j < 8; ++j) {
      const ushort4 u = *(const ushort4*)&vp[4 * j];
      VmT[4 * j + 0][y] = u.x; VmT[4 * j + 1][y] = u.y;
      VmT[4 * j + 2][y] = u.z; VmT[4 * j + 3][y] = u.w;
    }
  }
  const float mf = (m_mask[b * MMHC + y] == PAD_TOK) ? 0.0f : 1.0f;
  __syncthreads();
  #pragma unroll 4
  for (int r = 0; r < 32; ++r) {
    float a0 = 0, a1 = 0, a2 = 0, a3 = 0;
    #pragma unroll
    for (int j = 0; j < 8; ++j) {
      const float4 q4 = *(const float4*)&Qs[r][4 * j];
      a0 += q4.x * k[4 * j + 0]; a1 += q4.y * k[4 * j + 1];
      a2 += q4.z * k[4 * j + 2]; a3 += q4.w * k[4 * j + 3];
    }
    Ss[r][y] = (mf > 0.0f) ? ((a0 + a1) + (a2 + a3)) : MASK_SENT;
  }
  __syncthreads();
  const int wv = t >> 6, lane = t & 63;
  for (int r = wv; r < 32; r += 6) {
    float v[6];
    #pragma unroll
    for (int j = 0; j < 6; ++j) v[j] = Ss[r][lane + 64 * j];
    float mx = v[0];
    #pragma unroll
    for (int j = 1; j < 6; ++j) mx = fmaxf(mx, v[j]);
    #pragma unroll
    for (int off = 32; off; off >>= 1) mx = fmaxf(mx, __shfl_xor(mx, off));
    float e[6]; float tot = 0.0f;
    #pragma unroll
    for (int j = 0; j < 6; ++j) { e[j] = __expf(v[j] - mx); tot += e[j]; }
    #pragma unroll
    for (int off = 32; off; off >>= 1) tot += __shfl_xor(tot, off);
    const float inv = (tot > 0.0f) ? (1.0f / tot) : 0.0f;
    #pragma unroll
    for (int j = 0; j < 6; ++j) Ss[r][lane + 64 * j] = e[j] * inv;
  }
  __syncthreads();
  const int e = t & 31, rg = t >> 5;
  const int r0 = rg, r1 = rg + 12, r2 = rg + 24;
  const bool has2 = (rg < 8);
  float o0 = 0.0f, o1 = 0.0f, o2 = 0.0f;
  for (int yg = 0; yg < 48; ++yg) {
    float vv[8];
    {
      const u16* vp8 = &VmT[e][yg * 8];
      const ushort4 ua = *(const ushort4*)vp8;
      const ushort4 ub = *(const ushort4*)(vp8 + 4);
      vv[0] = bf2f(ua.x); vv[1] = bf2f(ua.y); vv[2] = bf2f(ua.z); vv[3] = bf2f(ua.w);
      vv[4] = bf2f(ub.x); vv[5] = bf2f(ub.y); vv[6] = bf2f(ub.z); vv[7] = bf2f(ub.w);
    }
    const float4 pa0 = *(const float4*)&Ss[r0][yg * 8];
    const float4 pb0 = *(const float4*)&Ss[r0][yg * 8 + 4];
    o0 += pa0.x * vv[0] + pa0.y * vv[1] + pa0.z * vv[2] + pa0.w * vv[3]
        + pb0.x * vv[4] + pb0.y * vv[5] + pb0.z * vv[6] + pb0.w * vv[7];
    const float4 pa1 = *(const float4*)&Ss[r1][yg * 8];
    const float4 pb1 = *(const float4*)&Ss[r1][yg * 8 + 4];
    o1 += pa1.x * vv[0] + pa1.y * vv[1] + pa1.z * vv[2] + pa1.w * vv[3]
        + pb1.x * vv[4] + pb1.y * vv[5] + pb1.z * vv[6] + pb1.w * vv[7];
    if (has2) {
      const float4 pa2 = *(const float4*)&Ss[r2][yg * 8];
      const float4 pb2 = *(const float4*)&Ss[r2][yg * 8 + 4];
      o2 += pa2.x * vv[0] + pa2.y * vv[1] + pa2.z * vv[2] + pa2.w * vv[3]
          + pb2.x * vv[4] + pb2.y * vv[5] + pb2.z * vv[6] + pb2.w * vv[7];
    }
  }
  {
    const size_t orow = (size_t)(b * S_) * 256 + h * 32 + e;
    const float g0 = bf2f(QKVG[base + (size_t)r0 * 1024 + 768 + e]);
    att[orow + (size_t)r0 * 256] = f2bf(o0 * pf[r0] / (1.0f + __expf(-g0)));
    const float g1 = bf2f(QKVG[base + (size_t)r1 * 1024 + 768 + e]);
    att[orow + (size_t)r1 * 256] = f2bf(o1 * pf[r1] / (1.0f + __expf(-g1)));
    if (has2) {
      const float g2 = bf2f(QKVG[base + (size_t)r2 * 1024 + 768 + e]);
      att[orow + (size_t)r2 * 256] = f2bf(o2 * pf[r2] / (1.0f + __expf(-g2)));
    }
  }
}

// ---------------------------------------------------------------------------
// Launch. All d_in fp32; d_out fp32. Workspace (ws_size-adaptive):
//   WT   @ 0        : 524288   (bf16)
//   WoT  @ 524288   : 131072   (bf16)
//   attx @ 655360   : BS*256*2 = 27262976  (bf16; LN1 out, then attention out)
//   QKVG @ 27918336 : nb*416*1024*2 per chunk; nb=128 (full batch, 137 MB
//   total) when ws_size allows — poison fill shows ws = 256 MiB, so the
//   full-batch path (7 dispatches) is the expected one.
// gemm2 writes fp32+bias into d_out; LN2 in-place on d_out.
// ---------------------------------------------------------------------------
extern "C" void kernel_launch(void* const* d_in, const int* in_sizes, int n_in,
                              void* d_out, int out_size, void* d_ws, size_t ws_size,
                              hipStream_t stream) {
  const float* x      = (const float*)d_in[0];
  const float* p_mask = (const float*)d_in[1];
  const float* m_mask = (const float*)d_in[2];
  const float* q_proj = (const float*)d_in[3];
  const float* k_proj = (const float*)d_in[4];
  const float* v_proj = (const float*)d_in[5];
  const float* g_proj = (const float*)d_in[6];
  const float* out_w  = (const float*)d_in[7];
  const float* out_b  = (const float*)d_in[8];
  const float* ln1_g  = (const float*)d_in[9];
  const float* ln1_b  = (const float*)d_in[10];
  const float* ln2_g  = (const float*)d_in[11];
  const float* ln2_b  = (const float*)d_in[12];

  char* ws = (char*)d_ws;
  u16* WT   = (u16*)(ws);
  u16* WoT  = (u16*)(ws + 524288);
  u16* attx = (u16*)(ws + 655360);
  u16* QKVG = (u16*)(ws + 27918336);
  float* outp = (float*)d_out;

  // pick chunk size (batches) from actual workspace size
  const size_t FIXED = 27918336;
  const size_t PER_B = (size_t)S_ * 1024 * 2;   // 851968
  int nb = 4;
  const int cands[6] = {128, 64, 32, 16, 8, 4};
  for (int i = 0; i < 6; ++i) {
    if (FIXED + (size_t)cands[i] * PER_B <= ws_size) { nb = cands[i]; break; }
  }
  const int nchunks = B_ / nb;

  hipLaunchKernelGGL(pack_w, dim3(1280), dim3(256), 0, stream,
                     q_proj, k_proj, v_proj, g_proj, out_w, WT, WoT);
  hipLaunchKernelGGL(ln_f2b, dim3(BS_ / 4), dim3(256), 0, stream,
                     x, attx, ln1_g, ln1_b);
  for (int c = 0; c < nchunks; ++c) {
    const int b0 = c * nb;
    const u16* Achunk = attx + (size_t)b0 * S_ * 256;
    hipLaunchKernelGGL((gemm_bt<false>), dim3(8, nb * S_ / 128), dim3(256), 0, stream,
                       Achunk, WT, (void*)QKVG, (const float*)nullptr, 1024);
    hipLaunchKernelGGL(att_mhc, dim3(nb * 8), dim3(384), 0, stream,
                       QKVG, p_mask, m_mask, attx, b0);
    hipLaunchKernelGGL(att_pep, dim3(nb * 8), dim3(384), 0, stream,
                       QKVG, p_mask, m_mask, attx, b0);
  }
  hipLaunchKernelGGL((gemm_bt<true>), dim3(2, BS_ / 128), dim3(256), 0, stream,
                     attx, WoT, (void*)outp, out_b, 256);
  hipLaunchKernelGGL(ln_f2f, dim3(BS_ / 4), dim3(256), 0, stream,
                     outp, outp, ln2_g, ln2_b);
}

// Round 6
// 348.332 us; speedup vs baseline: 1.1273x; 1.0017x over previous
//
#include <hip/hip_runtime.h>

typedef unsigned short u16;
typedef __bf16 bf16x8 __attribute__((ext_vector_type(8)));
typedef float f32x4 __attribute__((ext_vector_type(4)));

#define B_    128
#define S_    416
#define NPEP  32
#define MMHC  384
#define D_    256
#define H_    8
#define E_    32
#define O_    256
#define BS_   (B_ * S_)      /* 53248 */

#define PAD_TOK (-2.0f)
// Underflows exp() to exact 0, safe under any expf range reduction.
#define MASK_SENT (-3.0e4f)

typedef const __attribute__((address_space(1))) void cg_void;
typedef __attribute__((address_space(3))) void lds_void;

__device__ __forceinline__ float bf2f(u16 u) {
  union { unsigned int i; float f; } x; x.i = ((unsigned int)u) << 16; return x.f;
}
__device__ __forceinline__ u16 f2bf(float f) {
  union { float f; unsigned int i; } x; x.f = f;
  unsigned int i = x.i;
  return (u16)((i + 0x7FFFu + ((i >> 16) & 1u)) >> 16);  // RNE
}

// ---------------------------------------------------------------------------
// K0: pack weights fp32 -> bf16.
//  blocks 0..1023 : WT[col][d] = {q,k,v,g}_proj[h][d][e], col = p*256 + h*32 + e
//  blocks 1024..1279 : WoT[n][k] = out_w[k][n]
// ---------------------------------------------------------------------------
__global__ __launch_bounds__(256)
void pack_w(const float* __restrict__ q, const float* __restrict__ k,
            const float* __restrict__ v, const float* __restrict__ g,
            const float* __restrict__ ow, u16* __restrict__ WT, u16* __restrict__ WoT) {
  const int bx = blockIdx.x, t = threadIdx.x;
  if (bx < 1024) {
    const int col = bx;
    const int p = col >> 8, h = (col >> 5) & 7, e = col & 31;
    const float* src = (p == 0) ? q : (p == 1) ? k : (p == 2) ? v : g;
    WT[col * 256 + t] = f2bf(src[(h * 256 + t) * 32 + e]);
  } else {
    const int n = bx - 1024;
    WoT[n * 256 + t] = f2bf(ow[t * 256 + n]);
  }
}

// ---------------------------------------------------------------------------
// LN1: fp32 in -> bf16 out. One wave per row (256 cols), 4 rows/block.
// ---------------------------------------------------------------------------
__global__ __launch_bounds__(256)
void ln_f2b(const float* __restrict__ inp, u16* __restrict__ out,
            const float* __restrict__ gam, const float* __restrict__ bet) {
  const int w = threadIdx.x >> 6, lane = threadIdx.x & 63;
  const size_t row = (size_t)blockIdx.x * 4 + w;
  const float4 u = *((const float4*)inp + row * 64 + lane);
  const float x0 = u.x, x1 = u.y, x2 = u.z, x3 = u.w;
  float sum = (x0 + x1) + (x2 + x3);
  float ss  = (x0 * x0 + x1 * x1) + (x2 * x2 + x3 * x3);
  #pragma unroll
  for (int off = 32; off; off >>= 1) {
    sum += __shfl_xor(sum, off);
    ss  += __shfl_xor(ss, off);
  }
  const float mean = sum * 0.00390625f;
  float var = ss * 0.00390625f - mean * mean;
  var = fmaxf(var, 0.0f);
  const float rs = rsqrtf(var + 1e-6f);
  const float4 g4 = *((const float4*)gam + lane);
  const float4 b4 = *((const float4*)bet + lane);
  ushort4 r;
  r.x = f2bf((x0 - mean) * rs * g4.x + b4.x);
  r.y = f2bf((x1 - mean) * rs * g4.y + b4.y);
  r.z = f2bf((x2 - mean) * rs * g4.z + b4.z);
  r.w = f2bf((x3 - mean) * rs * g4.w + b4.w);
  *((ushort4*)out + row * 64 + lane) = r;
}

// ---------------------------------------------------------------------------
// GEMM1: QKVG = xln[53248 x 256] * WT^T, head-major scatter epilogue.
// Output: P[h][row][e] (bf16), P in {Qh,Kh,Vh,Gh} by col>>8, h=(col>>5)&7.
// 128x128 tile, 4 waves 2x2, global_load_lds(16B) + XOR-swizzled LDS.
// ---------------------------------------------------------------------------
__global__ __launch_bounds__(256, 2)
void gemm_qkvg(const u16* __restrict__ A, const u16* __restrict__ BT,
               u16* __restrict__ Qh, u16* __restrict__ Kh,
               u16* __restrict__ Vh, u16* __restrict__ Gh) {
  __shared__ __attribute__((aligned(16))) u16 As[128 * 64];
  __shared__ __attribute__((aligned(16))) u16 Bs[128 * 64];
  const int n0 = blockIdx.x * 128;
  const int m0 = blockIdx.y * 128;
  const int tid = threadIdx.x;
  const int lane = tid & 63;
  const int w = tid >> 6;
  const int wr = (w >> 1) * 64;
  const int wc = (w & 1) * 64;
  const int mi = lane & 15;
  const int quad = lane >> 4;
  const int rseg = lane >> 3;               // 0..7
  const int gcol = (lane & 7) ^ rseg;       // swizzled global 16B-granule
  f32x4 acc[4][4] = {};
  for (int kc = 0; kc < 256; kc += 64) {
    __syncthreads();
    #pragma unroll
    for (int j = 0; j < 4; ++j) {
      const int seg = w * 4 + j;            // 0..15, 8 rows each
      const int r = seg * 8 + rseg;
      const u16* ga = &A[(size_t)(m0 + r) * 256 + kc + gcol * 8];
      __builtin_amdgcn_global_load_lds((cg_void*)ga, (lds_void*)&As[seg * 512], 16, 0, 0);
      const u16* gb = &BT[(size_t)(n0 + r) * 256 + kc + gcol * 8];
      __builtin_amdgcn_global_load_lds((cg_void*)gb, (lds_void*)&Bs[seg * 512], 16, 0, 0);
    }
    __syncthreads();
    #pragma unroll
    for (int kt = 0; kt < 2; ++kt) {
      bf16x8 a[4], bb[4];
      #pragma unroll
      for (int i = 0; i < 4; ++i) {
        const int m = wr + i * 16 + mi;
        const int pg = (kt * 4 + quad) ^ (mi & 7);
        a[i] = *(const bf16x8*)&As[m * 64 + pg * 8];
      }
      #pragma unroll
      for (int i = 0; i < 4; ++i) {
        const int n = wc + i * 16 + mi;
        const int pg = (kt * 4 + quad) ^ (mi & 7);
        bb[i] = *(const bf16x8*)&Bs[n * 64 + pg * 8];
      }
      #pragma unroll
      for (int i = 0; i < 4; ++i)
        #pragma unroll
        for (int jn = 0; jn < 4; ++jn)
          acc[i][jn] = __builtin_amdgcn_mfma_f32_16x16x32_bf16(a[i], bb[jn], acc[i][jn], 0, 0, 0);
    }
  }
  // D: row = quad*4 + reg, col = lane&15. Scatter col -> P[h][row][e].
  #pragma unroll
  for (int jn = 0; jn < 4; ++jn) {
    const int colb = n0 + wc + jn * 16;     // wave-uniform 16-block
    const int p = colb >> 8;
    const int h = (colb >> 5) & 7;
    const int e = (colb & 16) + mi;
    u16* bp = (p == 0) ? Qh : (p == 1) ? Kh : (p == 2) ? Vh : Gh;
    u16* dst = bp + (size_t)h * BS_ * 32 + e;
    #pragma unroll
    for (int i = 0; i < 4; ++i) {
      const int row = m0 + wr + i * 16 + quad * 4;
      #pragma unroll
      for (int r = 0; r < 4; ++r)
        dst[(size_t)(row + r) * 32] = f2bf(acc[i][jn][r]);
    }
  }
}

// ---------------------------------------------------------------------------
// Attention, MHC rows: attend to the 32 peptide keys. One block per (b,h),
// 384 threads = one per row. Head-major inputs -> fully coalesced loads.
// ---------------------------------------------------------------------------
__global__ __launch_bounds__(384)
void att_mhc(const u16* __restrict__ Qh, const u16* __restrict__ Kh,
             const u16* __restrict__ Vh, const u16* __restrict__ Gh,
             const float* __restrict__ p_mask, const float* __restrict__ m_mask,
             u16* __restrict__ att) {
  __shared__ float Kp[32][32];
  __shared__ float Vp[32][32];
  __shared__ float pf[32];
  const int bh = blockIdx.x;
  const int b = bh >> 3, h = bh & 7;
  const int t = threadIdx.x;
  const size_t hb = (size_t)h * BS_ + (size_t)b * S_;   // row base for head h
  if (t < 256) {
    const int y = t >> 3, e0 = (t & 7) * 4;
    const ushort4 ku = *(const ushort4*)&Kh[(hb + y) * 32 + e0];
    Kp[y][e0 + 0] = bf2f(ku.x); Kp[y][e0 + 1] = bf2f(ku.y);
    Kp[y][e0 + 2] = bf2f(ku.z); Kp[y][e0 + 3] = bf2f(ku.w);
    const ushort4 vu = *(const ushort4*)&Vh[(hb + y) * 32 + e0];
    Vp[y][e0 + 0] = bf2f(vu.x); Vp[y][e0 + 1] = bf2f(vu.y);
    Vp[y][e0 + 2] = bf2f(vu.z); Vp[y][e0 + 3] = bf2f(vu.w);
  } else if (t < 288) {
    const int y = t - 256;
    pf[y] = (p_mask[b * NPEP + y] == PAD_TOK) ? 0.0f : 1.0f;
  }
  __syncthreads();
  const int x = 32 + t;
  float q[32];
  {
    const u16* qp = &Qh[(hb + x) * 32];
    #pragma unroll
    for (int j = 0; j < 8; ++j) {
      const ushort4 u = *(const ushort4*)&qp[4 * j];
      q[4 * j + 0] = bf2f(u.x); q[4 * j + 1] = bf2f(u.y);
      q[4 * j + 2] = bf2f(u.z); q[4 * j + 3] = bf2f(u.w);
    }
  }
  float s[32];
  #pragma unroll
  for (int y = 0; y < 32; ++y) {
    float a0 = 0, a1 = 0, a2 = 0, a3 = 0;
    #pragma unroll
    for (int j = 0; j < 8; ++j) {
      const float4 k4 = *(const float4*)&Kp[y][4 * j];
      a0 += q[4 * j + 0] * k4.x; a1 += q[4 * j + 1] * k4.y;
      a2 += q[4 * j + 2] * k4.z; a3 += q[4 * j + 3] * k4.w;
    }
    const float sv = ((a0 + a1) + (a2 + a3)) * 0.17677669529663687f; // 1/sqrt(32)
    s[y] = (pf[y] > 0.0f) ? sv : MASK_SENT;
  }
  float mx = MASK_SENT;
  #pragma unroll
  for (int y = 0; y < 32; ++y) mx = fmaxf(mx, s[y]);
  float tot = 0.0f;
  #pragma unroll
  for (int y = 0; y < 32; ++y) { s[y] = __expf(s[y] - mx); tot += s[y]; }
  const float inv = (tot > 0.0f) ? (1.0f / tot) : 0.0f;
  float o[32];
  #pragma unroll
  for (int e = 0; e < 32; ++e) o[e] = 0.0f;
  #pragma unroll
  for (int y = 0; y < 32; ++y) {
    const float p = s[y] * inv;
    #pragma unroll
    for (int j = 0; j < 8; ++j) {
      const float4 v4 = *(const float4*)&Vp[y][4 * j];
      o[4 * j + 0] += p * v4.x; o[4 * j + 1] += p * v4.y;
      o[4 * j + 2] += p * v4.z; o[4 * j + 3] += p * v4.w;
    }
  }
  const float rf = (m_mask[b * MMHC + t] == PAD_TOK) ? 0.0f : 1.0f;
  const u16* gp = &Gh[(hb + x) * 32];
  u16* op = &att[(size_t)(b * S_ + x) * 256 + h * 32];
  #pragma unroll
  for (int j = 0; j < 8; ++j) {
    const ushort4 gu = *(const ushort4*)&gp[4 * j];
    ushort4 r;
    r.x = f2bf(o[4 * j + 0] * rf / (1.0f + __expf(-bf2f(gu.x))));
    r.y = f2bf(o[4 * j + 1] * rf / (1.0f + __expf(-bf2f(gu.y))));
    r.z = f2bf(o[4 * j + 2] * rf / (1.0f + __expf(-bf2f(gu.z))));
    r.w = f2bf(o[4 * j + 3] * rf / (1.0f + __expf(-bf2f(gu.w))));
    *(ushort4*)&op[4 * j] = r;
  }
}

// ---------------------------------------------------------------------------
// Attention, peptide rows: attend to 384 MHC keys. One block per (b,h).
// Head-major inputs -> coalesced loads; rest identical to round 5.
// ---------------------------------------------------------------------------
__global__ __launch_bounds__(384)
void att_pep(const u16* __restrict__ Qh, const u16* __restrict__ Kh,
             const u16* __restrict__ Vh, const u16* __restrict__ Gh,
             const float* __restrict__ p_mask, const float* __restrict__ m_mask,
             u16* __restrict__ att) {
  __shared__ float Qs[32][32];
  __shared__ float Ss[32][392];
  __shared__ u16  VmT[32][392];   // row stride 784B = 49*16
  __shared__ float pf[32];
  const int bh = blockIdx.x;
  const int b = bh >> 3, h = bh & 7;
  const int t = threadIdx.x;
  const size_t hb = (size_t)h * BS_ + (size_t)b * S_;
  if (t < 256) {
    const int r = t >> 3, e0 = (t & 7) * 4;
    const ushort4 u = *(const ushort4*)&Qh[(hb + r) * 32 + e0];
    const float sc = 0.17677669529663687f;
    Qs[r][e0 + 0] = bf2f(u.x) * sc; Qs[r][e0 + 1] = bf2f(u.y) * sc;
    Qs[r][e0 + 2] = bf2f(u.z) * sc; Qs[r][e0 + 3] = bf2f(u.w) * sc;
  } else if (t < 288) {
    const int r = t - 256;
    pf[r] = (p_mask[b * NPEP + r] == PAD_TOK) ? 0.0f : 1.0f;
  }
  const int y = t;
  float k[32];
  {
    const u16* kp = &Kh[(hb + 32 + y) * 32];
    #pragma unroll
    for (int j = 0; j < 8; ++j) {
      const ushort4 u = *(const ushort4*)&kp[4 * j];
      k[4 * j + 0] = bf2f(u.x); k[4 * j + 1] = bf2f(u.y);
      k[4 * j + 2] = bf2f(u.z); k[4 * j + 3] = bf2f(u.w);
    }
    const u16* vp = &Vh[(hb + 32 + y) * 32];
    #pragma unroll
    for (int j = 0; j < 8; ++j) {
      const ushort4 u = *(const ushort4*)&vp[4 * j];
      VmT[4 * j + 0][y] = u.x; VmT[4 * j + 1][y] = u.y;
      VmT[4 * j + 2][y] = u.z; VmT[4 * j + 3][y] = u.w;
    }
  }
  const float mf = (m_mask[b * MMHC + y] == PAD_TOK) ? 0.0f : 1.0f;
  __syncthreads();
  #pragma unroll 4
  for (int r = 0; r < 32; ++r) {
    float a0 = 0, a1 = 0, a2 = 0, a3 = 0;
    #pragma unroll
    for (int j = 0; j < 8; ++j) {
      const float4 q4 = *(const float4*)&Qs[r][4 * j];
      a0 += q4.x * k[4 * j + 0]; a1 += q4.y * k[4 * j + 1];
      a2 += q4.z * k[4 * j + 2]; a3 += q4.w * k[4 * j + 3];
    }
    Ss[r][y] = (mf > 0.0f) ? ((a0 + a1) + (a2 + a3)) : MASK_SENT;
  }
  __syncthreads();
  const int wv = t >> 6, lane = t & 63;
  for (int r = wv; r < 32; r += 6) {
    float v[6];
    #pragma unroll
    for (int j = 0; j < 6; ++j) v[j] = Ss[r][lane + 64 * j];
    float mx = v[0];
    #pragma unroll
    for (int j = 1; j < 6; ++j) mx = fmaxf(mx, v[j]);
    #pragma unroll
    for (int off = 32; off; off >>= 1) mx = fmaxf(mx, __shfl_xor(mx, off));
    float e[6]; float tot = 0.0f;
    #pragma unroll
    for (int j = 0; j < 6; ++j) { e[j] = __expf(v[j] - mx); tot += e[j]; }
    #pragma unroll
    for (int off = 32; off; off >>= 1) tot += __shfl_xor(tot, off);
    const float inv = (tot > 0.0f) ? (1.0f / tot) : 0.0f;
    #pragma unroll
    for (int j = 0; j < 6; ++j) Ss[r][lane + 64 * j] = e[j] * inv;
  }
  __syncthreads();
  const int e = t & 31, rg = t >> 5;
  const int r0 = rg, r1 = rg + 12, r2 = rg + 24;
  const bool has2 = (rg < 8);
  float o0 = 0.0f, o1 = 0.0f, o2 = 0.0f;
  for (int yg = 0; yg < 48; ++yg) {
    float vv[8];
    {
      const u16* vp8 = &VmT[e][yg * 8];
      const ushort4 ua = *(const ushort4*)vp8;
      const ushort4 ub = *(const ushort4*)(vp8 + 4);
      vv[0] = bf2f(ua.x); vv[1] = bf2f(ua.y); vv[2] = bf2f(ua.z); vv[3] = bf2f(ua.w);
      vv[4] = bf2f(ub.x); vv[5] = bf2f(ub.y); vv[6] = bf2f(ub.z); vv[7] = bf2f(ub.w);
    }
    const float4 pa0 = *(const float4*)&Ss[r0][yg * 8];
    const float4 pb0 = *(const float4*)&Ss[r0][yg * 8 + 4];
    o0 += pa0.x * vv[0] + pa0.y * vv[1] + pa0.z * vv[2] + pa0.w * vv[3]
        + pb0.x * vv[4] + pb0.y * vv[5] + pb0.z * vv[6] + pb0.w * vv[7];
    const float4 pa1 = *(const float4*)&Ss[r1][yg * 8];
    const float4 pb1 = *(const float4*)&Ss[r1][yg * 8 + 4];
    o1 += pa1.x * vv[0] + pa1.y * vv[1] + pa1.z * vv[2] + pa1.w * vv[3]
        + pb1.x * vv[4] + pb1.y * vv[5] + pb1.z * vv[6] + pb1.w * vv[7];
    if (has2) {
      const float4 pa2 = *(const float4*)&Ss[r2][yg * 8];
      const float4 pb2 = *(const float4*)&Ss[r2][yg * 8 + 4];
      o2 += pa2.x * vv[0] + pa2.y * vv[1] + pa2.z * vv[2] + pa2.w * vv[3]
          + pb2.x * vv[4] + pb2.y * vv[5] + pb2.z * vv[6] + pb2.w * vv[7];
    }
  }
  {
    const size_t orow = (size_t)(b * S_) * 256 + h * 32 + e;
    const float g0 = bf2f(Gh[(hb + r0) * 32 + e]);
    att[orow + (size_t)r0 * 256] = f2bf(o0 * pf[r0] / (1.0f + __expf(-g0)));
    const float g1 = bf2f(Gh[(hb + r1) * 32 + e]);
    att[orow + (size_t)r1 * 256] = f2bf(o1 * pf[r1] / (1.0f + __expf(-g1)));
    if (has2) {
      const float g2 = bf2f(Gh[(hb + r2) * 32 + e]);
      att[orow + (size_t)r2 * 256] = f2bf(o2 * pf[r2] / (1.0f + __expf(-g2)));
    }
  }
}

// ---------------------------------------------------------------------------
// GEMM2 + bias + LN2 fused: out = LN(attx[53248x256] * WoT^T + bias).
// 128x256 tile per block (whole LN rows), 512 threads = 8 waves (2 row x 4
// col groups of 64x64). Row stats: quad-shuffle reduce over mi, then LDS
// cross-wave reduce, then apply LN and store fp32 directly to d_out.
// ---------------------------------------------------------------------------
__global__ __launch_bounds__(512, 2)
void gemm2_ln(const u16* __restrict__ A, const u16* __restrict__ BT,
              float* __restrict__ out, const float* __restrict__ bias,
              const float* __restrict__ gam, const float* __restrict__ bet) {
  __shared__ __attribute__((aligned(16))) u16 As[128 * 64];
  __shared__ __attribute__((aligned(16))) u16 Bs[256 * 64];
  __shared__ float rsum[128][4];
  __shared__ float rssq[128][4];
  __shared__ float mean_s[128], rstd_s[128];
  const int m0 = blockIdx.x * 128;
  const int tid = threadIdx.x;
  const int lane = tid & 63;
  const int w = tid >> 6;            // 0..7
  const int wr = (w >> 2) * 64;      // 0 / 64
  const int wc = (w & 3) * 64;       // 0,64,128,192
  const int mi = lane & 15;
  const int quad = lane >> 4;
  const int rseg = lane >> 3;
  const int gcol = (lane & 7) ^ rseg;
  f32x4 acc[4][4] = {};
  for (int kc = 0; kc < 256; kc += 64) {
    __syncthreads();
    #pragma unroll
    for (int j = 0; j < 2; ++j) {          // A: 16 segs of 8 rows
      const int seg = w * 2 + j;
      const int r = seg * 8 + rseg;
      const u16* ga = &A[(size_t)(m0 + r) * 256 + kc + gcol * 8];
      __builtin_amdgcn_global_load_lds((cg_void*)ga, (lds_void*)&As[seg * 512], 16, 0, 0);
    }
    #pragma unroll
    for (int j = 0; j < 4; ++j) {          // B: 32 segs of 8 rows
      const int seg = w * 4 + j;
      const int r = seg * 8 + rseg;
      const u16* gb = &BT[(size_t)r * 256 + kc + gcol * 8];
      __builtin_amdgcn_global_load_lds((cg_void*)gb, (lds_void*)&Bs[seg * 512], 16, 0, 0);
    }
    __syncthreads();
    #pragma unroll
    for (int kt = 0; kt < 2; ++kt) {
      bf16x8 a[4], bb[4];
      #pragma unroll
      for (int i = 0; i < 4; ++i) {
        const int m = wr + i * 16 + mi;
        const int pg = (kt * 4 + quad) ^ (mi & 7);
        a[i] = *(const bf16x8*)&As[m * 64 + pg * 8];
      }
      #pragma unroll
      for (int i = 0; i < 4; ++i) {
        const int n = wc + i * 16 + mi;
        const int pg = (kt * 4 + quad) ^ (mi & 7);
        bb[i] = *(const bf16x8*)&Bs[n * 64 + pg * 8];
      }
      #pragma unroll
      for (int i = 0; i < 4; ++i)
        #pragma unroll
        for (int jn = 0; jn < 4; ++jn)
          acc[i][jn] = __builtin_amdgcn_mfma_f32_16x16x32_bf16(a[i], bb[jn], acc[i][jn], 0, 0, 0);
    }
  }
  // bias per thread-column
  float bia[4];
  #pragma unroll
  for (int jn = 0; jn < 4; ++jn) bia[jn] = bias[wc + jn * 16 + mi];
  // row partial stats: sum over jn, reduce over mi (within quad)
  #pragma unroll
  for (int i = 0; i < 4; ++i) {
    #pragma unroll
    for (int r = 0; r < 4; ++r) {
      float s = 0.0f, qq = 0.0f;
      #pragma unroll
      for (int jn = 0; jn < 4; ++jn) {
        const float v = acc[i][jn][r] + bia[jn];
        s += v; qq += v * v;
      }
      #pragma unroll
      for (int off = 1; off < 16; off <<= 1) {
        s  += __shfl_xor(s, off);
        qq += __shfl_xor(qq, off);
      }
      if (mi == 0) {
        const int rl = wr + i * 16 + quad * 4 + r;
        rsum[rl][w & 3] = s;
        rssq[rl][w & 3] = qq;
      }
    }
  }
  __syncthreads();
  if (tid < 128) {
    const float s = rsum[tid][0] + rsum[tid][1] + rsum[tid][2] + rsum[tid][3];
    const float qq = rssq[tid][0] + rssq[tid][1] + rssq[tid][2] + rssq[tid][3];
    const float mean = s * 0.00390625f;
    float var = qq * 0.00390625f - mean * mean;
    var = fmaxf(var, 0.0f);
    mean_s[tid] = mean;
    rstd_s[tid] = rsqrtf(var + 1e-6f);
  }
  __syncthreads();
  #pragma unroll
  for (int jn = 0; jn < 4; ++jn) {
    const int col = wc + jn * 16 + mi;
    const float gv = gam[col], bv = bet[col];
    #pragma unroll
    for (int i = 0; i < 4; ++i) {
      #pragma unroll
      for (int r = 0; r < 4; ++r) {
        const int rl = wr + i * 16 + quad * 4 + r;
        const float v = acc[i][jn][r] + bia[jn];
        out[(size_t)(m0 + rl) * 256 + col] = (v - mean_s[rl]) * rstd_s[rl] * gv + bv;
      }
    }
  }
}

// ---------------------------------------------------------------------------
// Launch. All d_in fp32; d_out fp32. Workspace (full batch, ~137 MB; the
// harness poison fill showed ws = 256 MiB):
//   WT   @ 0         : 524288   (bf16)
//   WoT  @ 524288    : 131072   (bf16)
//   attx @ 655360    : BS*256*2 = 27262976  (bf16; LN1 out, then attn out)
//   Qh   @ 27918336  : 27262976 (bf16, [h][row][e])
//   Kh   @ 55181312  : 27262976
//   Vh   @ 82444288  : 27262976
//   Gh   @ 109707264 : 27262976    total 136970240
// ---------------------------------------------------------------------------
extern "C" void kernel_launch(void* const* d_in, const int* in_sizes, int n_in,
                              void* d_out, int out_size, void* d_ws, size_t ws_size,
                              hipStream_t stream) {
  const float* x      = (const float*)d_in[0];
  const float* p_mask = (const float*)d_in[1];
  const float* m_mask = (const float*)d_in[2];
  const float* q_proj = (const float*)d_in[3];
  const float* k_proj = (const float*)d_in[4];
  const float* v_proj = (const float*)d_in[5];
  const float* g_proj = (const float*)d_in[6];
  const float* out_w  = (const float*)d_in[7];
  const float* out_b  = (const float*)d_in[8];
  const float* ln1_g  = (const float*)d_in[9];
  const float* ln1_b  = (const float*)d_in[10];
  const float* ln2_g  = (const float*)d_in[11];
  const float* ln2_b  = (const float*)d_in[12];

  char* ws = (char*)d_ws;
  u16* WT   = (u16*)(ws);
  u16* WoT  = (u16*)(ws + 524288);
  u16* attx = (u16*)(ws + 655360);
  u16* Qh   = (u16*)(ws + 27918336);
  u16* Kh   = (u16*)(ws + 55181312);
  u16* Vh   = (u16*)(ws + 82444288);
  u16* Gh   = (u16*)(ws + 109707264);
  float* outp = (float*)d_out;

  hipLaunchKernelGGL(pack_w, dim3(1280), dim3(256), 0, stream,
                     q_proj, k_proj, v_proj, g_proj, out_w, WT, WoT);
  hipLaunchKernelGGL(ln_f2b, dim3(BS_ / 4), dim3(256), 0, stream,
                     x, attx, ln1_g, ln1_b);
  hipLaunchKernelGGL(gemm_qkvg, dim3(8, BS_ / 128), dim3(256), 0, stream,
                     attx, WT, Qh, Kh, Vh, Gh);
  hipLaunchKernelGGL(att_mhc, dim3(B_ * H_), dim3(384), 0, stream,
                     Qh, Kh, Vh, Gh, p_mask, m_mask, attx);
  hipLaunchKernelGGL(att_pep, dim3(B_ * H_), dim3(384), 0, stream,
                     Qh, Kh, Vh, Gh, p_mask, m_mask, attx);
  hipLaunchKernelGGL(gemm2_ln, dim3(BS_ / 128), dim3(512), 0, stream,
                     attx, WoT, outp, out_b, ln2_g, ln2_b);
}